// Round 1
// 3287.267 us; speedup vs baseline: 1.3864x; 1.3864x over previous
//
#include <hip/hip_runtime.h>
#include <math.h>

// ---------------------------------------------------------------------------
// N=50000 nodes, E=800000 edges, feat 64, msg hidden 128, 3 steps, 17 types.
// Round 3: all MLP GEMMs moved to bf16 MFMA (v_mfma_f32_16x16x32_bf16),
// fp32 accumulate. Weights pre-transposed/swizzled/bf16 into workspace
// images once per launch; activations kept as linear bf16 copies and
// gathered via global_load_lds with pre-swizzled per-lane source addresses.
// Layer1 computed transposed with a permuted output-row order so layer2's
// B-fragments are assembled purely in registers (no LDS round trip).
// ---------------------------------------------------------------------------

typedef unsigned short u16;
typedef __attribute__((ext_vector_type(8))) short short8;   // 8 bf16 = 4 VGPR
typedef __attribute__((ext_vector_type(4))) float f32x4;

__device__ __forceinline__ unsigned fkey(float f) {
    unsigned u = __float_as_uint(f);
    return (u & 0x80000000u) ? ~u : (u | 0x80000000u);
}
__device__ __forceinline__ float funkey(unsigned k) {
    return (k & 0x80000000u) ? __uint_as_float(k & 0x7FFFFFFFu) : __uint_as_float(~k);
}

// fp32 -> bf16 round-to-nearest-even
__device__ __forceinline__ u16 f2bf(float f) {
    unsigned u = __float_as_uint(f);
    return (u16)((u + 0x7FFFu + ((u >> 16) & 1u)) >> 16);
}
__device__ __forceinline__ unsigned pk2(float a, float b) {
    return (unsigned)f2bf(a) | ((unsigned)f2bf(b) << 16);
}
// async global->LDS, 16B per lane; LDS dest = uniform base + lane*16
__device__ __forceinline__ void gload16(const void* g, void* l) {
    __builtin_amdgcn_global_load_lds((const __attribute__((address_space(1))) void*)g,
                                     (__attribute__((address_space(3))) void*)l, 16, 0, 0);
}

// ---------------------------------------------------------------------------
// Weight image builder.
// Image layout: [K/32 chunks][Hd rows][4 slots][8 bf16], where slot holds
// k-granule kg = slot ^ ((row>>1)&3)  (bank-conflict swizzle).
// PERM (layer-1 only): image row rr holds source column
//   perm(rr) = 32*(hf>>1) + 8*q + 4*(hf&1) + r   (rr = 16hf + 4q + r)
// so that the D1 accumulator registers of lane-group q are exactly the
// 8-consecutive-h B-fragment elements layer 2 needs.
// ---------------------------------------------------------------------------
template<bool PERM>
__global__ void prep_w(const float* __restrict__ w, u16* __restrict__ img, int K, int Hd)
{
    int idx = blockIdx.x * 256 + threadIdx.x;
    if (idx >= K * Hd) return;
    int j = idx & 7, slot = (idx >> 3) & 3;
    int rest = idx >> 5;
    int rr = rest % Hd, ck = rest / Hd;
    int kk = ck * 32 + ((slot ^ ((rr >> 1) & 3)) << 3) + j;
    int col = rr;
    if (PERM) {
        int hf = rr >> 4, q = (rr >> 2) & 3, r = rr & 3;
        col = 32 * (hf >> 1) + 8 * q + 4 * (hf & 1) + r;
    }
    img[idx] = f2bf(w[(size_t)kk * Hd + col]);
}

// linear fp32 -> bf16 convert, 8 elems/thread
__global__ void f2bf_rows(const float* __restrict__ in, u16* __restrict__ out, size_t n8)
{
    size_t i = (size_t)blockIdx.x * 256 + threadIdx.x;
    if (i >= n8) return;
    const float* p = in + i * 8;
    f32x4 a = *(const f32x4*)p;
    f32x4 b = *(const f32x4*)(p + 4);
    uint4 o;
    o.x = pk2(a.x, a.y); o.y = pk2(a.z, a.w);
    o.z = pk2(b.x, b.y); o.w = pk2(b.z, b.w);
    *(uint4*)(out + i * 8) = o;
}

// ---------------------------------------------------------------------------
// MFMA 2-layer MLP: out[M][64] = relu(X[M][K1] @ w1 + b1) @ w2 + b2
// Computed transposed: D1[h][edge] = W1^T X^T ; D2[outc][edge] = W2^T relu(D1).
// Block: 256 thr / 4 waves, 128 rows (edges). Wave w owns edge cols
// [w*32, w*32+32) (2 col-frags) x all rows.
// GATHER: X row e = concat(nf[src[e]], nf[tgt[e]], ef[e]) (bf16 sources),
//         plus atomicAdd of the output into aggr[tgt[e]].
// outf/outb are nullable (fp32 / bf16 outputs).
// ---------------------------------------------------------------------------
template<int K1, int HID, bool GATHER>
__global__ __launch_bounds__(256)
void mfma_mlp2(const u16* __restrict__ A0b, const u16* __restrict__ efb,
               const int* __restrict__ srcI, const int* __restrict__ tgtI,
               const u16* __restrict__ w1img, const float* __restrict__ b1,
               const u16* __restrict__ w2img, const float* __restrict__ b2,
               float* __restrict__ outf, u16* __restrict__ outb,
               float* __restrict__ aggr, int M)
{
    constexpr int NHF = HID / 16;   // layer-1 row-frags
    constexpr int NC1 = K1 / 32;    // layer-1 k-chunks
    constexpr int NC2 = HID / 32;   // layer-2 k-chunks
    __shared__ __align__(16) u16 Xs[128 * 32];   // activations chunk (8KB)
    __shared__ __align__(16) u16 Ws[HID * 32];   // W1 image chunk
    __shared__ __align__(16) u16 W2s[HID * 64];  // full W2 image

    const int tid = threadIdx.x;
    const int w = tid >> 6, lane = tid & 63;
    const int q = lane >> 4, cc = lane & 15;
    const int e0 = blockIdx.x * 128;

    // stage full W2 image once (linear); drained at first barrier
#pragma unroll
    for (int i = 0; i < HID / 32; i++) {
        const int g0 = w * (HID * 2) + i * 64;
        gload16(w2img + (size_t)(g0 + lane) * 8, &W2s[(size_t)g0 * 8]);
    }

    // layer-1 accumulators, bias init (permuted row order)
    f32x4 acc1[NHF][2];
#pragma unroll
    for (int hf = 0; hf < NHF; hf++) {
        const f32x4 bv = *(const f32x4*)&b1[32 * (hf >> 1) + 8 * q + 4 * (hf & 1)];
        acc1[hf][0] = bv; acc1[hf][1] = bv;
    }

#pragma unroll
    for (int ck = 0; ck < NC1; ck++) {
        // ---- stage Xs: 512 granules of 16B, swizzled via source address ----
#pragma unroll
        for (int i = 0; i < 2; i++) {
            const int g = w * 128 + i * 64 + lane;
            const int r = g >> 2, slot = g & 3;
            const int kg = slot ^ ((r >> 1) & 3);
            int e = e0 + r; if (e >= M) e = M - 1;
            const u16* sp;
            if constexpr (GATHER) {
                const int region = ck >> 1;            // 0:nf[src] 1:nf[tgt] 2:ef
                const int col = (ck & 1) * 32 + kg * 8;
                const u16* base = (region == 2) ? efb : A0b;
                const int row = (region == 0) ? srcI[e] : (region == 1) ? tgtI[e] : e;
                sp = base + (size_t)row * 64 + col;
            } else {
                sp = A0b + (size_t)e * 64 + ck * 32 + kg * 8;
            }
            gload16(sp, &Xs[(size_t)(w * 128 + i * 64) * 8]);
        }
        // ---- stage W1 chunk (linear from pre-swizzled image) ----
#pragma unroll
        for (int i = 0; i < HID / 64; i++) {
            const int g0 = w * HID + i * 64;
            gload16(w1img + (size_t)ck * HID * 32 + (size_t)(g0 + lane) * 8,
                    &Ws[(size_t)g0 * 8]);
        }
        __syncthreads();

        // B-frags: activations, col = edge
        short8 xf[2];
#pragma unroll
        for (int n = 0; n < 2; n++) {
            const int er = w * 32 + n * 16 + cc;
            const int sl = q ^ ((er >> 1) & 3);
            xf[n] = *(const short8*)&Xs[(er * 4 + sl) * 8];
        }
        // A-frags: W1 rows (h), MFMA
#pragma unroll
        for (int hf = 0; hf < NHF; hf++) {
            const int rr = hf * 16 + cc;
            const int sl = q ^ ((rr >> 1) & 3);
            const short8 wa = *(const short8*)&Ws[(rr * 4 + sl) * 8];
            acc1[hf][0] = __builtin_amdgcn_mfma_f32_16x16x32_bf16(wa, xf[0], acc1[hf][0], 0, 0, 0);
            acc1[hf][1] = __builtin_amdgcn_mfma_f32_16x16x32_bf16(wa, xf[1], acc1[hf][1], 0, 0, 0);
        }
        __syncthreads();
    }

    // ---- relu + pack to bf16 pairs (pure register hand-off) ----
    unsigned P[NHF][2][2];
#pragma unroll
    for (int hf = 0; hf < NHF; hf++)
#pragma unroll
        for (int n = 0; n < 2; n++) {
            const f32x4 v = acc1[hf][n];
            P[hf][n][0] = pk2(fmaxf(v.x, 0.f), fmaxf(v.y, 0.f));
            P[hf][n][1] = pk2(fmaxf(v.z, 0.f), fmaxf(v.w, 0.f));
        }

    // ---- layer 2 ----
    f32x4 acc2[4][2];
#pragma unroll
    for (int of = 0; of < 4; of++) {
        const f32x4 bv = *(const f32x4*)&b2[of * 16 + 4 * q];
        acc2[of][0] = bv; acc2[of][1] = bv;
    }
#pragma unroll
    for (int c2 = 0; c2 < NC2; c2++) {
        short8 hb[2];
#pragma unroll
        for (int n = 0; n < 2; n++) {
            union { unsigned u[4]; short8 v; } t;
            t.u[0] = P[2 * c2][n][0];     t.u[1] = P[2 * c2][n][1];
            t.u[2] = P[2 * c2 + 1][n][0]; t.u[3] = P[2 * c2 + 1][n][1];
            hb[n] = t.v;
        }
#pragma unroll
        for (int of = 0; of < 4; of++) {
            const int o = of * 16 + cc;
            const int sl = q ^ ((o >> 1) & 3);
            const short8 wa = *(const short8*)&W2s[((c2 * 64 + o) * 4 + sl) * 8];
            acc2[of][0] = __builtin_amdgcn_mfma_f32_16x16x32_bf16(wa, hb[0], acc2[of][0], 0, 0, 0);
            acc2[of][1] = __builtin_amdgcn_mfma_f32_16x16x32_bf16(wa, hb[1], acc2[of][1], 0, 0, 0);
        }
    }

    // ---- epilogue: D2[outc][edge]; lane holds outc = of*16+4q+{0..3}, edge col cc
#pragma unroll
    for (int n = 0; n < 2; n++) {
        const int e = e0 + w * 32 + n * 16 + cc;
        if (e >= M) continue;
        int t = 0;
        if constexpr (GATHER) t = tgtI[e];
#pragma unroll
        for (int of = 0; of < 4; of++) {
            const f32x4 v = acc2[of][n];
            const int co = of * 16 + 4 * q;
            if (outf) *(f32x4*)&outf[(size_t)e * 64 + co] = v;
            if (outb) {
                uint2 u; u.x = pk2(v.x, v.y); u.y = pk2(v.z, v.w);
                *(uint2*)&outb[(size_t)e * 64 + co] = u;
            }
            if constexpr (GATHER) {
                float* ag = aggr + (size_t)t * 64 + co;
                atomicAdd(ag + 0, v.x); atomicAdd(ag + 1, v.y);
                atomicAdd(ag + 2, v.z); atomicAdd(ag + 3, v.w);
            }
        }
    }
}

// ---------------- small per-row helpers (fp32, unchanged) ------------------
__device__ __forceinline__ void accum_part64(const float* __restrict__ xp,
                                             const float* __restrict__ w, const int wld,
                                             float* __restrict__ h)
{
#pragma unroll 1
    for (int kc = 0; kc < 64; kc += 8) {
        float4 a = *(const float4*)(xp + kc);
        float4 b = *(const float4*)(xp + kc + 4);
        float xs[8] = {a.x, a.y, a.z, a.w, b.x, b.y, b.z, b.w};
        const float* __restrict__ wr = w + (size_t)kc * wld;
#pragma unroll
        for (int kk = 0; kk < 8; kk++) {
#pragma unroll
            for (int c = 0; c < 64; c++)
                h[c] = fmaf(xs[kk], wr[(size_t)kk * wld + c], h[c]);
        }
    }
}

__device__ __forceinline__ void store_row64(float* __restrict__ dst, const float* __restrict__ acc)
{
#pragma unroll
    for (int i = 0; i < 16; i++)
        ((float4*)dst)[i] = make_float4(acc[4 * i], acc[4 * i + 1], acc[4 * i + 2], acc[4 * i + 3]);
}

// ---------------- node update: nf' = concat(nf, aggr) @ nu_w1 + b ----------
// fp32 (keeps node-state precision across steps); also emits bf16 copy.
__global__ __launch_bounds__(64)
void node_update_kernel(const float* __restrict__ nf, const float* __restrict__ ag,
                        const float* __restrict__ w, const float* __restrict__ b,
                        float* __restrict__ out, u16* __restrict__ outb, int M)
{
    int r = blockIdx.x * 64 + threadIdx.x;
    if (r >= M) return;
    float acc[64];
#pragma unroll
    for (int c = 0; c < 64; c++) acc[c] = b[c];
    accum_part64(nf + (size_t)r * 64, w, 64, acc);
    accum_part64(ag + (size_t)r * 64, w + (size_t)64 * 64, 64, acc);
    store_row64(out + (size_t)r * 64, acc);
    if (outb) {
#pragma unroll
        for (int i = 0; i < 16; i++) {
            uint2 u;
            u.x = pk2(acc[4 * i + 0], acc[4 * i + 1]);
            u.y = pk2(acc[4 * i + 2], acc[4 * i + 3]);
            *(uint2*)&outb[(size_t)r * 64 + 4 * i] = u;
        }
    }
}

// ---------------- node heads (fp32, unchanged) ------------------------------
__global__ __launch_bounds__(256)
void heads_kernel(const float* __restrict__ nf,
                  const float* __restrict__ nc_w1, const float* __restrict__ nc_b1,
                  const float* __restrict__ nc_w2, const float* __restrict__ nc_b2,
                  const float* __restrict__ cl_w1, const float* __restrict__ cl_b1,
                  const float* __restrict__ cl_w2, const float* __restrict__ cl_b2,
                  const float* __restrict__ ce_w,  const float* __restrict__ ce_b,
                  float* __restrict__ node_pred, float* __restrict__ class_pred,
                  int* __restrict__ ntype, float* __restrict__ emb, int M)
{
    int r = blockIdx.x * blockDim.x + threadIdx.x;
    if (r >= M) return;
    const float* xp = nf + (size_t)r * 64;
    {
        float h[64];
#pragma unroll
        for (int c = 0; c < 64; c++) h[c] = nc_b1[c];
        accum_part64(xp, nc_w1, 64, h);
        float np = nc_b2[0];
#pragma unroll
        for (int k = 0; k < 64; k++) np = fmaf(fmaxf(h[k], 0.f), nc_w2[k], np);
        node_pred[r] = np;
    }
    {
        float h[64];
#pragma unroll
        for (int c = 0; c < 64; c++) h[c] = cl_b1[c];
        accum_part64(xp, cl_w1, 64, h);
        float cp[17];
#pragma unroll
        for (int j = 0; j < 17; j++) cp[j] = cl_b2[j];
#pragma unroll
        for (int k = 0; k < 64; k++) {
            float hv = fmaxf(h[k], 0.f);
#pragma unroll
            for (int j = 0; j < 17; j++) cp[j] = fmaf(hv, cl_w2[k * 17 + j], cp[j]);
        }
#pragma unroll
        for (int j = 0; j < 17; j++) class_pred[(size_t)r * 17 + j] = cp[j];
        float best = cp[0]; int bi = 0;          // jnp.argmax: first max index
#pragma unroll
        for (int j = 1; j < 17; j++) { if (cp[j] > best) { best = cp[j]; bi = j; } }
        ntype[r] = bi;
    }
    {
        float acc[64];
#pragma unroll
        for (int c = 0; c < 64; c++) acc[c] = ce_b[c];
        accum_part64(xp, ce_w, 64, acc);
        store_row64(emb + (size_t)r * 64, acc);
    }
}

// ---------------- segment-softmax passes (unchanged) -----------------------
__global__ void init_seg_kernel(unsigned* __restrict__ segmaxu, float* __restrict__ segsum, int n)
{
    int i = blockIdx.x * blockDim.x + threadIdx.x;
    if (i < n) { segmaxu[i] = 0x007FFFFFu /* fkey(-inf) */; segsum[i] = 0.f; }
}

__global__ __launch_bounds__(64)
void edge1_kernel(const float* __restrict__ ef,
                  const float* __restrict__ ec_w1, const float* __restrict__ ec_b1,
                  const float* __restrict__ ec_w2, const float* __restrict__ ec_b2,
                  const float* __restrict__ emb, const int* __restrict__ src,
                  const int* __restrict__ tgt, const int* __restrict__ ntype,
                  float* __restrict__ score, float* __restrict__ sigb,
                  int* __restrict__ seg, unsigned* __restrict__ segmaxu, int E)
{
    int e = blockIdx.x * 64 + threadIdx.x;
    if (e >= E) return;
    float h[64];
#pragma unroll
    for (int c = 0; c < 64; c++) h[c] = ec_b1[c];
    accum_part64(ef + (size_t)e * 64, ec_w1, 64, h);
    float ep = ec_b2[0];
#pragma unroll
    for (int k = 0; k < 64; k++) ep = fmaf(fmaxf(h[k], 0.f), ec_w2[k], ep);
    sigb[e] = 1.f / (1.f + expf(-ep));

    int s = src[e], t = tgt[e];
    const float* ea = emb + (size_t)s * 64;
    const float* eb = emb + (size_t)t * 64;
    float sc = 0.f;
#pragma unroll 1
    for (int kc = 0; kc < 64; kc += 4) {
        float4 ua = *(const float4*)(ea + kc);
        float4 ub = *(const float4*)(eb + kc);
        sc = fmaf(ua.x, ub.x, sc); sc = fmaf(ua.y, ub.y, sc);
        sc = fmaf(ua.z, ub.z, sc); sc = fmaf(ua.w, ub.w, sc);
    }
    score[e] = sc;
    int sg = t * 17 + ntype[s];
    seg[e] = sg;
    atomicMax(segmaxu + sg, fkey(sc));
}

__global__ void edge2_kernel(const float* __restrict__ score, const int* __restrict__ seg,
                             const unsigned* __restrict__ segmaxu, float* __restrict__ segsum,
                             float* __restrict__ exb, int E)
{
    int e = blockIdx.x * blockDim.x + threadIdx.x;
    if (e >= E) return;
    int sg = seg[e];
    float ex = expf(score[e] - funkey(segmaxu[sg]));
    exb[e] = ex;
    atomicAdd(segsum + sg, ex);
}

__global__ void edge3_kernel(const float* __restrict__ exb, const int* __restrict__ seg,
                             const float* __restrict__ segsum, const float* __restrict__ sigb,
                             float* __restrict__ out_edge, int E)
{
    int e = blockIdx.x * blockDim.x + threadIdx.x;
    if (e >= E) return;
    out_edge[e] = exb[e] / segsum[seg[e]] * sigb[e];
}

// ---------------------------------------------------------------------------
extern "C" void kernel_launch(void* const* d_in, const int* in_sizes, int n_in,
                              void* d_out, int out_size, void* d_ws, size_t ws_size,
                              hipStream_t stream)
{
    const float* x          = (const float*)d_in[0];
    const float* edge_attr  = (const float*)d_in[1];
    const int*   edge_index = (const int*)d_in[2];
    const float* ne_w1 = (const float*)d_in[4],  *ne_b1 = (const float*)d_in[5];
    const float* ne_w2 = (const float*)d_in[6],  *ne_b2 = (const float*)d_in[7];
    const float* ee_w1 = (const float*)d_in[8],  *ee_b1 = (const float*)d_in[9];
    const float* ee_w2 = (const float*)d_in[10], *ee_b2 = (const float*)d_in[11];
    const float* me_w1 = (const float*)d_in[12], *me_b1 = (const float*)d_in[13];
    const float* me_w2 = (const float*)d_in[14], *me_b2 = (const float*)d_in[15];
    const float* nu_w1 = (const float*)d_in[16], *nu_b1 = (const float*)d_in[17];
    const float* ec_w1 = (const float*)d_in[18], *ec_b1 = (const float*)d_in[19];
    const float* ec_w2 = (const float*)d_in[20], *ec_b2 = (const float*)d_in[21];
    const float* nc_w1 = (const float*)d_in[22], *nc_b1 = (const float*)d_in[23];
    const float* nc_w2 = (const float*)d_in[24], *nc_b2 = (const float*)d_in[25];
    const float* cl_w1 = (const float*)d_in[26], *cl_b1 = (const float*)d_in[27];
    const float* cl_w2 = (const float*)d_in[28], *cl_b2 = (const float*)d_in[29];
    const float* ce_w  = (const float*)d_in[30], *ce_b  = (const float*)d_in[31];

    const int N = in_sizes[3];
    const int E = in_sizes[2] / 2;
    const int* src = edge_index;
    const int* tgt = edge_index + E;

    float* out      = (float*)d_out;
    float* out_edge = out;                              // [E]
    float* out_np   = out + E;                          // [N]
    float* out_cp   = out_np + N;                       // [N,17]
    float* out_nf   = out_cp + (size_t)17 * N;          // [N,64]
    float* out_ef   = out_nf + (size_t)64 * N;          // [E,64]

    // ---- workspace carve (bytes, 256B aligned chunks) ----
    char* pc = (char*)d_ws;
    auto take = [&](size_t bytes) { char* r = pc; pc += (bytes + 255) & ~(size_t)255; return r; };
    float* nfA     = (float*)take((size_t)N * 64 * 4);
    float* nfB     = (float*)take((size_t)N * 64 * 4);
    float* aggr    = (float*)take((size_t)N * 64 * 4);
    float* emb     = (float*)take((size_t)N * 64 * 4);
    u16*   nfb     = (u16*)take((size_t)N * 64 * 2);    // bf16 node feats
    u16*   xb      = (u16*)take((size_t)N * 64 * 2);    // bf16 x
    u16*   ebA     = (u16*)take((size_t)E * 64 * 2);    // bf16 edge feats ping
    u16*   ebB     = (u16*)take((size_t)E * 64 * 2);    // bf16 edge feats pong
    u16*   wimg    = (u16*)take((size_t)49152 * 2);     // all weight images
    float* score   = (float*)take((size_t)E * 4);
    float* sigb    = (float*)take((size_t)E * 4);
    float* exb     = (float*)take((size_t)E * 4);
    float* segsum  = (float*)take((size_t)N * 17 * 4);
    unsigned* segmaxu = (unsigned*)take((size_t)N * 17 * 4);
    int*   seg     = (int*)take((size_t)E * 4);
    int*   ntype   = (int*)take((size_t)N * 4);

    u16* mW1i = wimg;               // 192*128 = 24576
    u16* mW2i = mW1i + 24576;       // 128*64  = 8192
    u16* nW1i = mW2i + 8192;        // 64*64   = 4096
    u16* nW2i = nW1i + 4096;
    u16* eW1i = nW2i + 4096;
    u16* eW2i = eW1i + 4096;

    // ---- weight images (transpose + swizzle + bf16; PERM on layer-1) ----
    prep_w<true ><<<(192 * 128 + 255) / 256, 256, 0, stream>>>(me_w1, mW1i, 192, 128);
    prep_w<false><<<(128 * 64  + 255) / 256, 256, 0, stream>>>(me_w2, mW2i, 128, 64);
    prep_w<true ><<<(64 * 64 + 255) / 256, 256, 0, stream>>>(ne_w1, nW1i, 64, 64);
    prep_w<false><<<(64 * 64 + 255) / 256, 256, 0, stream>>>(ne_w2, nW2i, 64, 64);
    prep_w<true ><<<(64 * 64 + 255) / 256, 256, 0, stream>>>(ee_w1, eW1i, 64, 64);
    prep_w<false><<<(64 * 64 + 255) / 256, 256, 0, stream>>>(ee_w2, eW2i, 64, 64);

    // ---- input bf16 copies ----
    f2bf_rows<<<(unsigned)(((size_t)N * 8 + 255) / 256), 256, 0, stream>>>(x, xb, (size_t)N * 8);
    f2bf_rows<<<(unsigned)(((size_t)E * 8 + 255) / 256), 256, 0, stream>>>(edge_attr, ebA, (size_t)E * 8);

    const int gN128 = (N + 127) / 128, gE128 = (E + 127) / 128;

    // ---- encoders (MFMA) ----
    mfma_mlp2<64, 64, false><<<gN128, 256, 0, stream>>>(
        xb, nullptr, nullptr, nullptr, nW1i, ne_b1, nW2i, ne_b2, nfA, nfb, nullptr, N);
    mfma_mlp2<64, 64, false><<<gE128, 256, 0, stream>>>(
        ebA, nullptr, nullptr, nullptr, eW1i, ee_b1, eW2i, ee_b2, nullptr, ebB, nullptr, E);

    // ---- 3 MPN steps ----
    // ef bf16 ping-pong: step0 reads ebB writes ebA; step1 ebA->ebB; step2 ebB->out_ef(fp32)
    const u16* efr[3] = {ebB, ebA, ebB};
    u16*       efw[3] = {ebA, ebB, nullptr};
    float*     nfd[3] = {nfB, nfA, out_nf};
    const float* nf_cur = nfA;
    for (int st = 0; st < 3; st++) {
        hipMemsetAsync(aggr, 0, (size_t)N * 64 * sizeof(float), stream);
        mfma_mlp2<192, 128, true><<<gE128, 256, 0, stream>>>(
            nfb, efr[st], src, tgt, mW1i, me_b1, mW2i, me_b2,
            (st == 2) ? out_ef : nullptr, efw[st], aggr, E);
        node_update_kernel<<<(N + 63) / 64, 64, 0, stream>>>(
            nf_cur, aggr, nu_w1, nu_b1, nfd[st], (st == 2) ? nullptr : nfb, N);
        nf_cur = nfd[st];
    }

    // ---- heads + type-constrained scatter-softmax (fp32, unchanged) ----
    heads_kernel<<<(N + 255) / 256, 256, 0, stream>>>(out_nf,
        nc_w1, nc_b1, nc_w2, nc_b2, cl_w1, cl_b1, cl_w2, cl_b2, ce_w, ce_b,
        out_np, out_cp, ntype, emb, N);
    init_seg_kernel<<<(N * 17 + 255) / 256, 256, 0, stream>>>(segmaxu, segsum, N * 17);
    edge1_kernel<<<(E + 63) / 64, 64, 0, stream>>>(out_ef, ec_w1, ec_b1, ec_w2, ec_b2,
                                                   emb, src, tgt, ntype, score, sigb, seg, segmaxu, E);
    edge2_kernel<<<(E + 255) / 256, 256, 0, stream>>>(score, seg, segmaxu, segsum, exb, E);
    edge3_kernel<<<(E + 255) / 256, 256, 0, stream>>>(exb, seg, segsum, sigb, out_edge, E);
}

// Round 2
// 1794.677 us; speedup vs baseline: 2.5395x; 1.8317x over previous
//
#include <hip/hip_runtime.h>
#include <math.h>

// ---------------------------------------------------------------------------
// N=50000 nodes, E=800000 edges, feat 64, msg hidden 128, 3 steps, 17 types.
// Round 4: remove the 51.2M device-scope fp32 atomics (the R3 bottleneck:
// WRITE_SIZE ~1GB/dispatch was memory-side atomic RMW traffic).
// Replacement: CSR-by-target permutation built once (hist + scan + scatter),
// then a gather-side segment-sum kernel (one wave per node, coalesced 128B
// bf16 row reads, fp32 register accumulate, linear writes). MFMA MLPs from
// R3 kept unchanged except the epilogue atomics are deleted.
// ---------------------------------------------------------------------------

typedef unsigned short u16;
typedef __attribute__((ext_vector_type(8))) short short8;   // 8 bf16 = 4 VGPR
typedef __attribute__((ext_vector_type(4))) float f32x4;

__device__ __forceinline__ unsigned fkey(float f) {
    unsigned u = __float_as_uint(f);
    return (u & 0x80000000u) ? ~u : (u | 0x80000000u);
}
__device__ __forceinline__ float funkey(unsigned k) {
    return (k & 0x80000000u) ? __uint_as_float(k & 0x7FFFFFFFu) : __uint_as_float(~k);
}

// fp32 -> bf16 round-to-nearest-even
__device__ __forceinline__ u16 f2bf(float f) {
    unsigned u = __float_as_uint(f);
    return (u16)((u + 0x7FFFu + ((u >> 16) & 1u)) >> 16);
}
__device__ __forceinline__ unsigned pk2(float a, float b) {
    return (unsigned)f2bf(a) | ((unsigned)f2bf(b) << 16);
}
__device__ __forceinline__ float bf2f(u16 v) {
    return __uint_as_float((unsigned)v << 16);
}
// async global->LDS, 16B per lane; LDS dest = uniform base + lane*16
__device__ __forceinline__ void gload16(const void* g, void* l) {
    __builtin_amdgcn_global_load_lds((const __attribute__((address_space(1))) void*)g,
                                     (__attribute__((address_space(3))) void*)l, 16, 0, 0);
}

// ---------------------------------------------------------------------------
// Weight image builder (unchanged from R3).
// ---------------------------------------------------------------------------
template<bool PERM>
__global__ void prep_w(const float* __restrict__ w, u16* __restrict__ img, int K, int Hd)
{
    int idx = blockIdx.x * 256 + threadIdx.x;
    if (idx >= K * Hd) return;
    int j = idx & 7, slot = (idx >> 3) & 3;
    int rest = idx >> 5;
    int rr = rest % Hd, ck = rest / Hd;
    int kk = ck * 32 + ((slot ^ ((rr >> 1) & 3)) << 3) + j;
    int col = rr;
    if (PERM) {
        int hf = rr >> 4, q = (rr >> 2) & 3, r = rr & 3;
        col = 32 * (hf >> 1) + 8 * q + 4 * (hf & 1) + r;
    }
    img[idx] = f2bf(w[(size_t)kk * Hd + col]);
}

// linear fp32 -> bf16 convert, 8 elems/thread
__global__ void f2bf_rows(const float* __restrict__ in, u16* __restrict__ out, size_t n8)
{
    size_t i = (size_t)blockIdx.x * 256 + threadIdx.x;
    if (i >= n8) return;
    const float* p = in + i * 8;
    f32x4 a = *(const f32x4*)p;
    f32x4 b = *(const f32x4*)(p + 4);
    uint4 o;
    o.x = pk2(a.x, a.y); o.y = pk2(a.z, a.w);
    o.z = pk2(b.x, b.y); o.w = pk2(b.z, b.w);
    *(uint4*)(out + i * 8) = o;
}

// ---------------------------------------------------------------------------
// CSR-by-target build: hist -> 2-level exclusive scan -> ranked scatter.
// Runs once per launch; reused by all 3 MPN steps.
// ---------------------------------------------------------------------------
__global__ void seg_count(const int* __restrict__ tgt, int* __restrict__ cnt, int E)
{
    int e = blockIdx.x * 256 + threadIdx.x;
    if (e < E) atomicAdd(&cnt[tgt[e]], 1);
}

__global__ void seg_part(const int* __restrict__ cnt, int* __restrict__ part, int N)
{
    __shared__ int s[256];
    int i = blockIdx.x * 256 + threadIdx.x;
    s[threadIdx.x] = (i < N) ? cnt[i] : 0;
    __syncthreads();
#pragma unroll
    for (int d = 128; d > 0; d >>= 1) {
        if (threadIdx.x < d) s[threadIdx.x] += s[threadIdx.x + d];
        __syncthreads();
    }
    if (threadIdx.x == 0) part[blockIdx.x] = s[0];
}

// single block; NB <= 256. Converts part[] to exclusive prefix; writes off[N]=E.
__global__ void seg_scanpart(int* __restrict__ part, int NB, int* __restrict__ offN, int E)
{
    __shared__ int s[256];
    int v = (threadIdx.x < NB) ? part[threadIdx.x] : 0;
    s[threadIdx.x] = v;
    __syncthreads();
#pragma unroll
    for (int d = 1; d < 256; d <<= 1) {
        int t = (threadIdx.x >= d) ? s[threadIdx.x - d] : 0;
        __syncthreads();
        s[threadIdx.x] += t;
        __syncthreads();
    }
    if (threadIdx.x < NB) part[threadIdx.x] = s[threadIdx.x] - v;   // exclusive
    if (threadIdx.x == 0) offN[0] = E;
}

__global__ void seg_off(const int* __restrict__ cnt, const int* __restrict__ part,
                        int* __restrict__ off, int N)
{
    __shared__ int s[256];
    int i = blockIdx.x * 256 + threadIdx.x;
    int v = (i < N) ? cnt[i] : 0;
    s[threadIdx.x] = v;
    __syncthreads();
#pragma unroll
    for (int d = 1; d < 256; d <<= 1) {
        int t = (threadIdx.x >= d) ? s[threadIdx.x - d] : 0;
        __syncthreads();
        s[threadIdx.x] += t;
        __syncthreads();
    }
    if (i < N) off[i] = part[blockIdx.x] + s[threadIdx.x] - v;      // exclusive
}

__global__ void seg_scatter(const int* __restrict__ tgt, const int* __restrict__ off,
                            int* __restrict__ cur, int* __restrict__ eperm, int E)
{
    int e = blockIdx.x * 256 + threadIdx.x;
    if (e >= E) return;
    int t = tgt[e];
    int p = off[t] + atomicAdd(&cur[t], 1);
    eperm[p] = e;
}

// ---------------------------------------------------------------------------
// Gather-side segment sum: aggr[t][c] = sum over incident edges of m_bf16[e][c].
// One wave per node; lane = column. Each m-row read = one coalesced 128B load.
// ---------------------------------------------------------------------------
__global__ __launch_bounds__(256)
void agg_kernel(const u16* __restrict__ m, const int* __restrict__ eperm,
                const int* __restrict__ off, float* __restrict__ aggr, int N)
{
    int t = blockIdx.x * 4 + (threadIdx.x >> 6);
    int lane = threadIdx.x & 63;
    if (t >= N) return;
    int b = off[t], e = off[t + 1];
    float a0 = 0.f, a1 = 0.f;
    int j = b;
    for (; j + 1 < e; j += 2) {
        int e0 = eperm[j], e1 = eperm[j + 1];
        a0 += bf2f(m[(size_t)e0 * 64 + lane]);
        a1 += bf2f(m[(size_t)e1 * 64 + lane]);
    }
    if (j < e) a0 += bf2f(m[(size_t)eperm[j] * 64 + lane]);
    aggr[(size_t)t * 64 + lane] = a0 + a1;
}

// ---------------------------------------------------------------------------
// MFMA 2-layer MLP (R3 structure; atomics removed, src/tgt loads hoisted).
// ---------------------------------------------------------------------------
template<int K1, int HID, bool GATHER>
__global__ __launch_bounds__(256)
void mfma_mlp2(const u16* __restrict__ A0b, const u16* __restrict__ efb,
               const int* __restrict__ srcI, const int* __restrict__ tgtI,
               const u16* __restrict__ w1img, const float* __restrict__ b1,
               const u16* __restrict__ w2img, const float* __restrict__ b2,
               float* __restrict__ outf, u16* __restrict__ outb, int M)
{
    constexpr int NHF = HID / 16;   // layer-1 row-frags
    constexpr int NC1 = K1 / 32;    // layer-1 k-chunks
    constexpr int NC2 = HID / 32;   // layer-2 k-chunks
    __shared__ __align__(16) u16 Xs[128 * 32];   // activations chunk (8KB)
    __shared__ __align__(16) u16 Ws[HID * 32];   // W1 image chunk
    __shared__ __align__(16) u16 W2s[HID * 64];  // full W2 image

    const int tid = threadIdx.x;
    const int w = tid >> 6, lane = tid & 63;
    const int q = lane >> 4, cc = lane & 15;
    const int e0 = blockIdx.x * 128;

    // stage full W2 image once (linear); drained at first barrier
#pragma unroll
    for (int i = 0; i < HID / 32; i++) {
        const int g0 = w * (HID * 2) + i * 64;
        gload16(w2img + (size_t)(g0 + lane) * 8, &W2s[(size_t)g0 * 8]);
    }

    // staging-lane row assignment (fixed across chunks): hoist src/tgt loads
    int ec[2], sA[2], tA[2];
#pragma unroll
    for (int i = 0; i < 2; i++) {
        const int g = w * 128 + i * 64 + lane;
        const int r = g >> 2;
        int e = e0 + r; if (e >= M) e = M - 1;
        ec[i] = e;
        if constexpr (GATHER) { sA[i] = srcI[e]; tA[i] = tgtI[e]; }
    }

    // layer-1 accumulators, bias init (permuted row order)
    f32x4 acc1[NHF][2];
#pragma unroll
    for (int hf = 0; hf < NHF; hf++) {
        const f32x4 bv = *(const f32x4*)&b1[32 * (hf >> 1) + 8 * q + 4 * (hf & 1)];
        acc1[hf][0] = bv; acc1[hf][1] = bv;
    }

#pragma unroll
    for (int ck = 0; ck < NC1; ck++) {
        // ---- stage Xs: 512 granules of 16B, swizzled via source address ----
#pragma unroll
        for (int i = 0; i < 2; i++) {
            const int g = w * 128 + i * 64 + lane;
            const int r = g >> 2, slot = g & 3;
            const int kg = slot ^ ((r >> 1) & 3);
            const u16* sp;
            if constexpr (GATHER) {
                const int region = ck >> 1;            // 0:nf[src] 1:nf[tgt] 2:ef
                const int col = (ck & 1) * 32 + kg * 8;
                const u16* base = (region == 2) ? efb : A0b;
                const int row = (region == 0) ? sA[i] : (region == 1) ? tA[i] : ec[i];
                sp = base + (size_t)row * 64 + col;
            } else {
                sp = A0b + (size_t)ec[i] * 64 + ck * 32 + kg * 8;
            }
            gload16(sp, &Xs[(size_t)(w * 128 + i * 64) * 8]);
        }
        // ---- stage W1 chunk (linear from pre-swizzled image) ----
#pragma unroll
        for (int i = 0; i < HID / 64; i++) {
            const int g0 = w * HID + i * 64;
            gload16(w1img + (size_t)ck * HID * 32 + (size_t)(g0 + lane) * 8,
                    &Ws[(size_t)g0 * 8]);
        }
        __syncthreads();

        // B-frags: activations, col = edge
        short8 xf[2];
#pragma unroll
        for (int n = 0; n < 2; n++) {
            const int er = w * 32 + n * 16 + cc;
            const int sl = q ^ ((er >> 1) & 3);
            xf[n] = *(const short8*)&Xs[(er * 4 + sl) * 8];
        }
        // A-frags: W1 rows (h), MFMA
#pragma unroll
        for (int hf = 0; hf < NHF; hf++) {
            const int rr = hf * 16 + cc;
            const int sl = q ^ ((rr >> 1) & 3);
            const short8 wa = *(const short8*)&Ws[(rr * 4 + sl) * 8];
            acc1[hf][0] = __builtin_amdgcn_mfma_f32_16x16x32_bf16(wa, xf[0], acc1[hf][0], 0, 0, 0);
            acc1[hf][1] = __builtin_amdgcn_mfma_f32_16x16x32_bf16(wa, xf[1], acc1[hf][1], 0, 0, 0);
        }
        __syncthreads();
    }

    // ---- relu + pack to bf16 pairs (pure register hand-off) ----
    unsigned P[NHF][2][2];
#pragma unroll
    for (int hf = 0; hf < NHF; hf++)
#pragma unroll
        for (int n = 0; n < 2; n++) {
            const f32x4 v = acc1[hf][n];
            P[hf][n][0] = pk2(fmaxf(v.x, 0.f), fmaxf(v.y, 0.f));
            P[hf][n][1] = pk2(fmaxf(v.z, 0.f), fmaxf(v.w, 0.f));
        }

    // ---- layer 2 ----
    f32x4 acc2[4][2];
#pragma unroll
    for (int of = 0; of < 4; of++) {
        const f32x4 bv = *(const f32x4*)&b2[of * 16 + 4 * q];
        acc2[of][0] = bv; acc2[of][1] = bv;
    }
#pragma unroll
    for (int c2 = 0; c2 < NC2; c2++) {
        short8 hb[2];
#pragma unroll
        for (int n = 0; n < 2; n++) {
            union { unsigned u[4]; short8 v; } t;
            t.u[0] = P[2 * c2][n][0];     t.u[1] = P[2 * c2][n][1];
            t.u[2] = P[2 * c2 + 1][n][0]; t.u[3] = P[2 * c2 + 1][n][1];
            hb[n] = t.v;
        }
#pragma unroll
        for (int of = 0; of < 4; of++) {
            const int o = of * 16 + cc;
            const int sl = q ^ ((o >> 1) & 3);
            const short8 wa = *(const short8*)&W2s[((c2 * 64 + o) * 4 + sl) * 8];
            acc2[of][0] = __builtin_amdgcn_mfma_f32_16x16x32_bf16(wa, hb[0], acc2[of][0], 0, 0, 0);
            acc2[of][1] = __builtin_amdgcn_mfma_f32_16x16x32_bf16(wa, hb[1], acc2[of][1], 0, 0, 0);
        }
    }

    // ---- epilogue: D2[outc][edge]; lane holds outc = of*16+4q+{0..3}, edge col cc
#pragma unroll
    for (int n = 0; n < 2; n++) {
        const int e = e0 + w * 32 + n * 16 + cc;
        if (e >= M) continue;
#pragma unroll
        for (int of = 0; of < 4; of++) {
            const f32x4 v = acc2[of][n];
            const int co = of * 16 + 4 * q;
            if (outf) *(f32x4*)&outf[(size_t)e * 64 + co] = v;
            if (outb) {
                uint2 u; u.x = pk2(v.x, v.y); u.y = pk2(v.z, v.w);
                *(uint2*)&outb[(size_t)e * 64 + co] = u;
            }
        }
    }
}

// ---------------- small per-row helpers (fp32, unchanged) ------------------
__device__ __forceinline__ void accum_part64(const float* __restrict__ xp,
                                             const float* __restrict__ w, const int wld,
                                             float* __restrict__ h)
{
#pragma unroll 1
    for (int kc = 0; kc < 64; kc += 8) {
        float4 a = *(const float4*)(xp + kc);
        float4 b = *(const float4*)(xp + kc + 4);
        float xs[8] = {a.x, a.y, a.z, a.w, b.x, b.y, b.z, b.w};
        const float* __restrict__ wr = w + (size_t)kc * wld;
#pragma unroll
        for (int kk = 0; kk < 8; kk++) {
#pragma unroll
            for (int c = 0; c < 64; c++)
                h[c] = fmaf(xs[kk], wr[(size_t)kk * wld + c], h[c]);
        }
    }
}

__device__ __forceinline__ void store_row64(float* __restrict__ dst, const float* __restrict__ acc)
{
#pragma unroll
    for (int i = 0; i < 16; i++)
        ((float4*)dst)[i] = make_float4(acc[4 * i], acc[4 * i + 1], acc[4 * i + 2], acc[4 * i + 3]);
}

// ---------------- node update: nf' = concat(nf, aggr) @ nu_w1 + b ----------
__global__ __launch_bounds__(64)
void node_update_kernel(const float* __restrict__ nf, const float* __restrict__ ag,
                        const float* __restrict__ w, const float* __restrict__ b,
                        float* __restrict__ out, u16* __restrict__ outb, int M)
{
    int r = blockIdx.x * 64 + threadIdx.x;
    if (r >= M) return;
    float acc[64];
#pragma unroll
    for (int c = 0; c < 64; c++) acc[c] = b[c];
    accum_part64(nf + (size_t)r * 64, w, 64, acc);
    accum_part64(ag + (size_t)r * 64, w + (size_t)64 * 64, 64, acc);
    store_row64(out + (size_t)r * 64, acc);
    if (outb) {
#pragma unroll
        for (int i = 0; i < 16; i++) {
            uint2 u;
            u.x = pk2(acc[4 * i + 0], acc[4 * i + 1]);
            u.y = pk2(acc[4 * i + 2], acc[4 * i + 3]);
            *(uint2*)&outb[(size_t)r * 64 + 4 * i] = u;
        }
    }
}

// ---------------- node heads (fp32, unchanged) ------------------------------
__global__ __launch_bounds__(256)
void heads_kernel(const float* __restrict__ nf,
                  const float* __restrict__ nc_w1, const float* __restrict__ nc_b1,
                  const float* __restrict__ nc_w2, const float* __restrict__ nc_b2,
                  const float* __restrict__ cl_w1, const float* __restrict__ cl_b1,
                  const float* __restrict__ cl_w2, const float* __restrict__ cl_b2,
                  const float* __restrict__ ce_w,  const float* __restrict__ ce_b,
                  float* __restrict__ node_pred, float* __restrict__ class_pred,
                  int* __restrict__ ntype, float* __restrict__ emb, int M)
{
    int r = blockIdx.x * blockDim.x + threadIdx.x;
    if (r >= M) return;
    const float* xp = nf + (size_t)r * 64;
    {
        float h[64];
#pragma unroll
        for (int c = 0; c < 64; c++) h[c] = nc_b1[c];
        accum_part64(xp, nc_w1, 64, h);
        float np = nc_b2[0];
#pragma unroll
        for (int k = 0; k < 64; k++) np = fmaf(fmaxf(h[k], 0.f), nc_w2[k], np);
        node_pred[r] = np;
    }
    {
        float h[64];
#pragma unroll
        for (int c = 0; c < 64; c++) h[c] = cl_b1[c];
        accum_part64(xp, cl_w1, 64, h);
        float cp[17];
#pragma unroll
        for (int j = 0; j < 17; j++) cp[j] = cl_b2[j];
#pragma unroll
        for (int k = 0; k < 64; k++) {
            float hv = fmaxf(h[k], 0.f);
#pragma unroll
            for (int j = 0; j < 17; j++) cp[j] = fmaf(hv, cl_w2[k * 17 + j], cp[j]);
        }
#pragma unroll
        for (int j = 0; j < 17; j++) class_pred[(size_t)r * 17 + j] = cp[j];
        float best = cp[0]; int bi = 0;          // jnp.argmax: first max index
#pragma unroll
        for (int j = 1; j < 17; j++) { if (cp[j] > best) { best = cp[j]; bi = j; } }
        ntype[r] = bi;
    }
    {
        float acc[64];
#pragma unroll
        for (int c = 0; c < 64; c++) acc[c] = ce_b[c];
        accum_part64(xp, ce_w, 64, acc);
        store_row64(emb + (size_t)r * 64, acc);
    }
}

// ---------------- segment-softmax passes (unchanged) -----------------------
__global__ void init_seg_kernel(unsigned* __restrict__ segmaxu, float* __restrict__ segsum, int n)
{
    int i = blockIdx.x * blockDim.x + threadIdx.x;
    if (i < n) { segmaxu[i] = 0x007FFFFFu /* fkey(-inf) */; segsum[i] = 0.f; }
}

__global__ __launch_bounds__(64)
void edge1_kernel(const float* __restrict__ ef,
                  const float* __restrict__ ec_w1, const float* __restrict__ ec_b1,
                  const float* __restrict__ ec_w2, const float* __restrict__ ec_b2,
                  const float* __restrict__ emb, const int* __restrict__ src,
                  const int* __restrict__ tgt, const int* __restrict__ ntype,
                  float* __restrict__ score, float* __restrict__ sigb,
                  int* __restrict__ seg, unsigned* __restrict__ segmaxu, int E)
{
    int e = blockIdx.x * 64 + threadIdx.x;
    if (e >= E) return;
    float h[64];
#pragma unroll
    for (int c = 0; c < 64; c++) h[c] = ec_b1[c];
    accum_part64(ef + (size_t)e * 64, ec_w1, 64, h);
    float ep = ec_b2[0];
#pragma unroll
    for (int k = 0; k < 64; k++) ep = fmaf(fmaxf(h[k], 0.f), ec_w2[k], ep);
    sigb[e] = 1.f / (1.f + expf(-ep));

    int s = src[e], t = tgt[e];
    const float* ea = emb + (size_t)s * 64;
    const float* eb = emb + (size_t)t * 64;
    float sc = 0.f;
#pragma unroll 1
    for (int kc = 0; kc < 64; kc += 4) {
        float4 ua = *(const float4*)(ea + kc);
        float4 ub = *(const float4*)(eb + kc);
        sc = fmaf(ua.x, ub.x, sc); sc = fmaf(ua.y, ub.y, sc);
        sc = fmaf(ua.z, ub.z, sc); sc = fmaf(ua.w, ub.w, sc);
    }
    score[e] = sc;
    int sg = t * 17 + ntype[s];
    seg[e] = sg;
    atomicMax(segmaxu + sg, fkey(sc));
}

__global__ void edge2_kernel(const float* __restrict__ score, const int* __restrict__ seg,
                             const unsigned* __restrict__ segmaxu, float* __restrict__ segsum,
                             float* __restrict__ exb, int E)
{
    int e = blockIdx.x * blockDim.x + threadIdx.x;
    if (e >= E) return;
    int sg = seg[e];
    float ex = expf(score[e] - funkey(segmaxu[sg]));
    exb[e] = ex;
    atomicAdd(segsum + sg, ex);
}

__global__ void edge3_kernel(const float* __restrict__ exb, const int* __restrict__ seg,
                             const float* __restrict__ segsum, const float* __restrict__ sigb,
                             float* __restrict__ out_edge, int E)
{
    int e = blockIdx.x * blockDim.x + threadIdx.x;
    if (e >= E) return;
    out_edge[e] = exb[e] / segsum[seg[e]] * sigb[e];
}

// ---------------------------------------------------------------------------
extern "C" void kernel_launch(void* const* d_in, const int* in_sizes, int n_in,
                              void* d_out, int out_size, void* d_ws, size_t ws_size,
                              hipStream_t stream)
{
    const float* x          = (const float*)d_in[0];
    const float* edge_attr  = (const float*)d_in[1];
    const int*   edge_index = (const int*)d_in[2];
    const float* ne_w1 = (const float*)d_in[4],  *ne_b1 = (const float*)d_in[5];
    const float* ne_w2 = (const float*)d_in[6],  *ne_b2 = (const float*)d_in[7];
    const float* ee_w1 = (const float*)d_in[8],  *ee_b1 = (const float*)d_in[9];
    const float* ee_w2 = (const float*)d_in[10], *ee_b2 = (const float*)d_in[11];
    const float* me_w1 = (const float*)d_in[12], *me_b1 = (const float*)d_in[13];
    const float* me_w2 = (const float*)d_in[14], *me_b2 = (const float*)d_in[15];
    const float* nu_w1 = (const float*)d_in[16], *nu_b1 = (const float*)d_in[17];
    const float* ec_w1 = (const float*)d_in[18], *ec_b1 = (const float*)d_in[19];
    const float* ec_w2 = (const float*)d_in[20], *ec_b2 = (const float*)d_in[21];
    const float* nc_w1 = (const float*)d_in[22], *nc_b1 = (const float*)d_in[23];
    const float* nc_w2 = (const float*)d_in[24], *nc_b2 = (const float*)d_in[25];
    const float* cl_w1 = (const float*)d_in[26], *cl_b1 = (const float*)d_in[27];
    const float* cl_w2 = (const float*)d_in[28], *cl_b2 = (const float*)d_in[29];
    const float* ce_w  = (const float*)d_in[30], *ce_b  = (const float*)d_in[31];

    const int N = in_sizes[3];
    const int E = in_sizes[2] / 2;
    const int* src = edge_index;
    const int* tgt = edge_index + E;

    float* out      = (float*)d_out;
    float* out_edge = out;                              // [E]
    float* out_np   = out + E;                          // [N]
    float* out_cp   = out_np + N;                       // [N,17]
    float* out_nf   = out_cp + (size_t)17 * N;          // [N,64]
    float* out_ef   = out_nf + (size_t)64 * N;          // [E,64]

    // ---- workspace carve (bytes, 256B aligned chunks) ----
    char* pc = (char*)d_ws;
    auto take = [&](size_t bytes) { char* r = pc; pc += (bytes + 255) & ~(size_t)255; return r; };
    float* nfA     = (float*)take((size_t)N * 64 * 4);
    float* nfB     = (float*)take((size_t)N * 64 * 4);
    float* aggr    = (float*)take((size_t)N * 64 * 4);
    float* emb     = (float*)take((size_t)N * 64 * 4);
    u16*   nfb     = (u16*)take((size_t)N * 64 * 2);    // bf16 node feats
    u16*   xb      = (u16*)take((size_t)N * 64 * 2);    // bf16 x
    u16*   ebA     = (u16*)take((size_t)E * 64 * 2);    // bf16 edge feats ping
    u16*   ebB     = (u16*)take((size_t)E * 64 * 2);    // bf16 edge feats pong
    u16*   wimg    = (u16*)take((size_t)49152 * 2);     // all weight images
    float* score   = (float*)take((size_t)E * 4);
    float* sigb    = (float*)take((size_t)E * 4);
    float* exb     = (float*)take((size_t)E * 4);
    float* segsum  = (float*)take((size_t)N * 17 * 4);
    unsigned* segmaxu = (unsigned*)take((size_t)N * 17 * 4);
    int*   seg     = (int*)take((size_t)E * 4);
    int*   ntype   = (int*)take((size_t)N * 4);
    int*   cnt     = (int*)take((size_t)N * 4);         // CSR build
    int*   cur     = (int*)take((size_t)N * 4);
    int*   part    = (int*)take((size_t)256 * 4);
    int*   off     = (int*)take((size_t)(N + 1) * 4);
    int*   eperm   = (int*)take((size_t)E * 4);

    u16* mW1i = wimg;               // 192*128 = 24576
    u16* mW2i = mW1i + 24576;       // 128*64  = 8192
    u16* nW1i = mW2i + 8192;        // 64*64   = 4096
    u16* nW2i = nW1i + 4096;
    u16* eW1i = nW2i + 4096;
    u16* eW2i = eW1i + 4096;

    const int gE256 = (E + 255) / 256;
    const int NB = (N + 255) / 256;                     // <= 256 required

    // ---- CSR-by-target build (once; reused by all 3 steps) ----
    hipMemsetAsync(cnt, 0, (size_t)N * 4, stream);
    hipMemsetAsync(cur, 0, (size_t)N * 4, stream);
    seg_count<<<gE256, 256, 0, stream>>>(tgt, cnt, E);
    seg_part<<<NB, 256, 0, stream>>>(cnt, part, N);
    seg_scanpart<<<1, 256, 0, stream>>>(part, NB, off + N, E);
    seg_off<<<NB, 256, 0, stream>>>(cnt, part, off, N);
    seg_scatter<<<gE256, 256, 0, stream>>>(tgt, off, cur, eperm, E);

    // ---- weight images (transpose + swizzle + bf16; PERM on layer-1) ----
    prep_w<true ><<<(192 * 128 + 255) / 256, 256, 0, stream>>>(me_w1, mW1i, 192, 128);
    prep_w<false><<<(128 * 64  + 255) / 256, 256, 0, stream>>>(me_w2, mW2i, 128, 64);
    prep_w<true ><<<(64 * 64 + 255) / 256, 256, 0, stream>>>(ne_w1, nW1i, 64, 64);
    prep_w<false><<<(64 * 64 + 255) / 256, 256, 0, stream>>>(ne_w2, nW2i, 64, 64);
    prep_w<true ><<<(64 * 64 + 255) / 256, 256, 0, stream>>>(ee_w1, eW1i, 64, 64);
    prep_w<false><<<(64 * 64 + 255) / 256, 256, 0, stream>>>(ee_w2, eW2i, 64, 64);

    // ---- input bf16 copies ----
    f2bf_rows<<<(unsigned)(((size_t)N * 8 + 255) / 256), 256, 0, stream>>>(x, xb, (size_t)N * 8);
    f2bf_rows<<<(unsigned)(((size_t)E * 8 + 255) / 256), 256, 0, stream>>>(edge_attr, ebA, (size_t)E * 8);

    const int gN128 = (N + 127) / 128, gE128 = (E + 127) / 128;

    // ---- encoders (MFMA) ----
    mfma_mlp2<64, 64, false><<<gN128, 256, 0, stream>>>(
        xb, nullptr, nullptr, nullptr, nW1i, ne_b1, nW2i, ne_b2, nfA, nfb, N);
    mfma_mlp2<64, 64, false><<<gE128, 256, 0, stream>>>(
        ebA, nullptr, nullptr, nullptr, eW1i, ee_b1, eW2i, ee_b2, nullptr, ebB, E);

    // ---- 3 MPN steps ----
    // ef bf16 ping-pong: step0 ebB->ebA, step1 ebA->ebB, step2 ebB->ebA (+out_ef fp32)
    const u16* efr[3] = {ebB, ebA, ebB};
    u16*       efw[3] = {ebA, ebB, ebA};
    float*     nfd[3] = {nfB, nfA, out_nf};
    const float* nf_cur = nfA;
    for (int st = 0; st < 3; st++) {
        mfma_mlp2<192, 128, true><<<gE128, 256, 0, stream>>>(
            nfb, efr[st], src, tgt, mW1i, me_b1, mW2i, me_b2,
            (st == 2) ? out_ef : nullptr, efw[st], E);
        agg_kernel<<<(N + 3) / 4, 256, 0, stream>>>(efw[st], eperm, off, aggr, N);
        node_update_kernel<<<(N + 63) / 64, 64, 0, stream>>>(
            nf_cur, aggr, nu_w1, nu_b1, nfd[st], (st == 2) ? nullptr : nfb, N);
        nf_cur = nfd[st];
    }

    // ---- heads + type-constrained scatter-softmax (fp32, unchanged) ----
    heads_kernel<<<(N + 255) / 256, 256, 0, stream>>>(out_nf,
        nc_w1, nc_b1, nc_w2, nc_b2, cl_w1, cl_b1, cl_w2, cl_b2, ce_w, ce_b,
        out_np, out_cp, ntype, emb, N);
    init_seg_kernel<<<(N * 17 + 255) / 256, 256, 0, stream>>>(segmaxu, segsum, N * 17);
    edge1_kernel<<<(E + 63) / 64, 64, 0, stream>>>(out_ef, ec_w1, ec_b1, ec_w2, ec_b2,
                                                   emb, src, tgt, ntype, score, sigb, seg, segmaxu, E);
    edge2_kernel<<<(E + 255) / 256, 256, 0, stream>>>(score, seg, segmaxu, segsum, exb, E);
    edge3_kernel<<<(E + 255) / 256, 256, 0, stream>>>(exb, seg, segsum, sigb, out_edge, E);
}